// Round 4
// baseline (201.119 us; speedup 1.0000x reference)
//
#include <hip/hip_runtime.h>
#include <hip/hip_bf16.h>

// MDTA: LN -> 1x1 conv (QKV) -> dw3x3 -> spatial attention (N=4096, d=24, 8 heads) -> proj + residual
// Flash attention: S^T-formulation (P exits MFMA in b64-packable layout), fixed-bound softmax,
// row-sum via ones-row in V, no K/V LDS staging (direct L2 reads, zero barriers in K-loop).

typedef __bf16 bf16;
typedef __bf16 bf16x2 __attribute__((ext_vector_type(2)));
typedef __bf16 bf16x4 __attribute__((ext_vector_type(4)));
typedef __bf16 bf16x8 __attribute__((ext_vector_type(8)));
typedef float f32x4 __attribute__((ext_vector_type(4)));

#define C_DIM 192
#define N_PIX 4096
#define HEADS 8
#define DHEAD 24
#define DPAD 32
#define C3 576
#define NSPLIT 3

__device__ inline float fast_exp2(float x) {
#if __has_builtin(__builtin_amdgcn_exp2f)
    return __builtin_amdgcn_exp2f(x);
#else
    return exp2f(x);
#endif
}

__device__ inline f32x4 mfma16(bf16x8 a, bf16x8 b, f32x4 c) {
    return __builtin_amdgcn_mfma_f32_16x16x32_bf16(a, b, c, 0, 0, 0);
}

// ---------------- merged: LayerNorm (blocks 0..255) + weight prep (blocks 256..687) ----------------
__global__ __launch_bounds__(256) void prep_ln(const float* __restrict__ x,
                                               const float* __restrict__ gamma,
                                               const float* __restrict__ beta,
                                               bf16* __restrict__ xln_t,
                                               const float* __restrict__ wqkv,
                                               const float* __restrict__ wproj,
                                               bf16* __restrict__ wqkv_b,
                                               bf16* __restrict__ wproj_b,
                                               float* __restrict__ maxk2) {
    int b = blockIdx.x, t = threadIdx.x;
    if (b >= 256) {
        int idx = (b - 256) * 256 + t;
        if (idx < C3 * C_DIM) wqkv_b[idx] = (bf16)wqkv[idx];
        if (idx < C_DIM * C_DIM) wproj_b[idx] = (bf16)wproj[idx];
        if (b == 256 && t < 8) maxk2[t] = 0.0f;
        return;
    }
    __shared__ float sred[256], ssred[256];
    int pixg = t & 15, cg = t >> 4;          // 16 pixels x 16 channel-groups of 12
    int p = b * 16 + pixg;
    float v[12];
    float s = 0.f, ss = 0.f;
    for (int j = 0; j < 12; ++j) {
        float f = x[(cg * 12 + j) * N_PIX + p];
        v[j] = f; s += f; ss += f * f;
    }
    sred[t] = s; ssred[t] = ss;
    __syncthreads();
    float S = 0.f, SS = 0.f;
    for (int k = 0; k < 16; ++k) { S += sred[k * 16 + pixg]; SS += ssred[k * 16 + pixg]; }
    float mean = S * (1.0f / C_DIM);
    float var = SS * (1.0f / C_DIM) - mean * mean;
    float rstd = rsqrtf(var + 1e-5f);
    for (int g = 0; g < 3; ++g) {
        bf16x4 w;
        for (int j = 0; j < 4; ++j) {
            int c = cg * 12 + g * 4 + j;
            w[j] = (bf16)((v[g * 4 + j] - mean) * rstd * gamma[c] + beta[c]);
        }
        *(bf16x4*)(xln_t + p * C_DIM + cg * 12 + g * 4) = w;
    }
}

// ---------------- GEMM (64x64 tile): out[M,4096] = A[M,192] * BT[4096,192]^T -> bf16 ----------------
__global__ __launch_bounds__(256) void gemm192(const bf16* __restrict__ A,
                                               const bf16* __restrict__ BT,
                                               bf16* __restrict__ outb) {
    const int K = 192;
    int n0 = blockIdx.x * 64;
    int m0 = blockIdx.y * 64;
    int tid = threadIdx.x;
    int wave = tid >> 6, lane = tid & 63;
    int l16 = lane & 15, quad = lane >> 4;
    int wm = (wave >> 1) * 32, wn = (wave & 1) * 32;
    f32x4 acc[2][2] = {};
    for (int kk = 0; kk < K; kk += 32) {
        bf16x8 a0 = *(const bf16x8*)(A + (m0 + wm + l16) * K + kk + quad * 8);
        bf16x8 a1 = *(const bf16x8*)(A + (m0 + wm + 16 + l16) * K + kk + quad * 8);
        bf16x8 b0 = *(const bf16x8*)(BT + (n0 + wn + l16) * K + kk + quad * 8);
        bf16x8 b1 = *(const bf16x8*)(BT + (n0 + wn + 16 + l16) * K + kk + quad * 8);
        acc[0][0] = mfma16(a0, b0, acc[0][0]);
        acc[0][1] = mfma16(a0, b1, acc[0][1]);
        acc[1][0] = mfma16(a1, b0, acc[1][0]);
        acc[1][1] = mfma16(a1, b1, acc[1][1]);
    }
    for (int i = 0; i < 2; ++i)
        for (int j = 0; j < 2; ++j)
            for (int r = 0; r < 4; ++r) {
                int row = m0 + wm + i * 16 + quad * 4 + r;
                int col = n0 + wn + j * 16 + l16;
                outb[row * N_PIX + col] = (bf16)acc[i][j][r];
            }
}

// ---------------- proj GEMM (64m x 32n tile) + fp32 residual epilogue ----------------
__global__ __launch_bounds__(256) void gemm_proj(const bf16* __restrict__ A,
                                                 const bf16* __restrict__ BT,
                                                 float* __restrict__ outf,
                                                 const float* __restrict__ resid) {
    const int K = 192;
    int n0 = blockIdx.x * 32;
    int m0 = blockIdx.y * 64;
    int tid = threadIdx.x;
    int wave = tid >> 6, lane = tid & 63;
    int l16 = lane & 15, quad = lane >> 4;
    int mrow = m0 + wave * 16;
    f32x4 acc[2] = {};
    for (int kk = 0; kk < K; kk += 32) {
        bf16x8 a = *(const bf16x8*)(A + (mrow + l16) * K + kk + quad * 8);
        bf16x8 b0 = *(const bf16x8*)(BT + (n0 + l16) * K + kk + quad * 8);
        bf16x8 b1 = *(const bf16x8*)(BT + (n0 + 16 + l16) * K + kk + quad * 8);
        acc[0] = mfma16(a, b0, acc[0]);
        acc[1] = mfma16(a, b1, acc[1]);
    }
    for (int j = 0; j < 2; ++j)
        for (int r = 0; r < 4; ++r) {
            int row = mrow + quad * 4 + r;
            int col = n0 + j * 16 + l16;
            outf[row * N_PIX + col] = acc[j][r] + resid[row * N_PIX + col];
        }
}

// ---------------- depthwise 3x3 + bias -> q/k [h][n][32-pad], v [h][32-pad][n] ----------------
// grid 24*64: (part,h) x image-row. 256 threads = 64 pixels x 4 channel-groups of 6.
// v row 24 is set to ONES (row-sum trick), rows 25..31 zero. q/k dd 24..31 zero.
__global__ __launch_bounds__(256) void dwconv(const bf16* __restrict__ qkv,
                                              const float* __restrict__ wdw,
                                              const float* __restrict__ bdw,
                                              bf16* __restrict__ qt,
                                              bf16* __restrict__ kt,
                                              bf16* __restrict__ vl,
                                              float* __restrict__ maxk2) {
    __shared__ float k2s[4][64];
    int bh = blockIdx.x >> 6;              // 0..23 = part*8 + h
    int y = blockIdx.x & 63;
    int part = bh >> 3, h = bh & 7;
    int cg = threadIdx.x >> 6, px = threadIdx.x & 63;
    int p = y * 64 + px;
    int ch0 = part * C_DIM + h * DHEAD + cg * 6;

    float acc[6];
    for (int j = 0; j < 6; ++j) {
        int ch = ch0 + j;
        const bf16* in = qkv + ch * N_PIX;
        const float* w = wdw + ch * 9;
        float a = bdw[ch];
        for (int dy = -1; dy <= 1; ++dy) {
            int yy = y + dy;
            if (yy < 0 || yy > 63) continue;
            for (int dx = -1; dx <= 1; ++dx) {
                int xc = px + dx;
                if (xc < 0 || xc > 63) continue;
                a += w[(dy + 1) * 3 + (dx + 1)] * (float)in[yy * 64 + xc];
            }
        }
        acc[j] = a;
    }

    if (part < 2) {
        bf16* base = (part == 0 ? qt : kt) + ((size_t)(h * N_PIX + p)) * DPAD;
        bf16* dst = base + cg * 6;
        for (int g = 0; g < 3; ++g) {
            bf16x2 w2; w2[0] = (bf16)acc[g * 2]; w2[1] = (bf16)acc[g * 2 + 1];
            *(bf16x2*)(dst + g * 2) = w2;
        }
        if (cg == 3) {
            // FIX: zero pad dd 24..31 of THIS row in the array this block owns
            bf16x8 z;
            for (int j = 0; j < 8; ++j) z[j] = (bf16)0.0f;
            *(bf16x8*)(base + 24) = z;
        }
        if (part == 1) {
            float s2 = 0.f;
            for (int j = 0; j < 6; ++j) s2 += acc[j] * acc[j];
            k2s[cg][px] = s2;
        }
        __syncthreads();
        if (part == 1 && cg == 0) {
            float tot = k2s[0][px] + k2s[1][px] + k2s[2][px] + k2s[3][px];
            for (int off = 1; off < 64; off <<= 1)
                tot = fmaxf(tot, __shfl_xor(tot, off, 64));
            if (px == 0) atomicMax((unsigned int*)(maxk2 + h), __float_as_uint(tot));
        }
    } else {
        __syncthreads();   // keep barrier uniform across the block
        for (int j = 0; j < 6; ++j)
            vl[((size_t)(h * DPAD + cg * 6 + j)) * N_PIX + p] = (bf16)acc[j];
        // pad rows: 24=ones, 25..31=zero
        if (cg == 0) vl[((size_t)(h * DPAD + 24)) * N_PIX + p] = (bf16)1.0f;
        vl[((size_t)(h * DPAD + 25 + cg)) * N_PIX + p] = (bf16)0.0f;
        if (cg < 3) vl[((size_t)(h * DPAD + 29 + cg)) * N_PIX + p] = (bf16)0.0f;
    }
}

// ---------------- flash attention: S^T form, fixed-bound softmax, no barriers ----------------
// Block = 1 head x 64 queries x 1/3 of keys. Wave owns 16 queries (cols of S^T).
// S^T = mfma(K_frag, Q_frag): lane(q,l) holds S^T[m=mt*16+q*4+r][n=l].
// P packed to per-wave LDS in chunked layout -> conflict-free b128 B-operand reads.
// O^T = mfma(V^T_frag, P_frag): row d, col n. V row 24 = ones gives l=sum(P) free.
__global__ __launch_bounds__(256, 6) void flash_attn(const bf16* __restrict__ qt,
                                                     const bf16* __restrict__ kt,
                                                     const bf16* __restrict__ vl,
                                                     const float* __restrict__ temp,
                                                     const float* __restrict__ maxk2,
                                                     bf16* __restrict__ opart,
                                                     float* __restrict__ lpart) {
    __shared__ __align__(16) bf16 Plds[4 * 1024];   // 2KB per wave: [mchunk(8)][n(16)][8]

    int tid = threadIdx.x;
    int wave = tid >> 6, lane = tid & 63;
    int l16 = lane & 15, quad = lane >> 4;
    int head = blockIdx.x & 7;
    int qb = (blockIdx.x >> 3) & 63;
    int split = blockIdx.x >> 9;
    int nbase = qb * 64 + wave * 16;
    int t0 = (split * 64) / NSPLIT, t1 = ((split + 1) * 64) / NSPLIT;
    float tl = temp[head] * 1.44269504f;

    // Q fragment (B-operand): B[n=l16][k=quad*8+j]
    bf16x8 aq = *(const bf16x8*)(qt + ((size_t)(head * N_PIX) + nbase + l16) * DPAD + quad * 8);

    // per-lane bound: B = |tl| * ||q_n|| * max||k|| + 1   (n = l16)
    float q2 = 0.f;
    for (int j = 0; j < 8; ++j) { float f = (float)aq[j]; q2 += f * f; }
    q2 += __shfl_xor(q2, 16, 64);
    q2 += __shfl_xor(q2, 32, 64);
    float Bb = fabsf(tl) * sqrtf(q2 * maxk2[head]) + 1.0f;

    const bf16* kbase = kt + (size_t)(head * N_PIX) * DPAD;
    const bf16* vbase = vl + (size_t)(head * DPAD) * N_PIX;
    bf16* pw = Plds + wave * 1024;

    f32x4 o0 = {0.f, 0.f, 0.f, 0.f}, o1 = {0.f, 0.f, 0.f, 0.f};

    for (int it = t0; it < t1; ++it) {
        int m0 = it * 64;
        // K fragments (A-operand for S^T): contiguous 1KB wave sweep per mt
        bf16x8 ak0 = *(const bf16x8*)(kbase + (size_t)(m0 + l16) * DPAD + quad * 8);
        bf16x8 ak1 = *(const bf16x8*)(kbase + (size_t)(m0 + 16 + l16) * DPAD + quad * 8);
        bf16x8 ak2 = *(const bf16x8*)(kbase + (size_t)(m0 + 32 + l16) * DPAD + quad * 8);
        bf16x8 ak3 = *(const bf16x8*)(kbase + (size_t)(m0 + 48 + l16) * DPAD + quad * 8);
        // V fragments (A-operand for O^T): d rows 0..15 and 16..31, k = m
        bf16x8 av0l = *(const bf16x8*)(vbase + (size_t)l16 * N_PIX + m0 + quad * 8);
        bf16x8 av0h = *(const bf16x8*)(vbase + (size_t)(16 + l16) * N_PIX + m0 + quad * 8);
        bf16x8 av1l = *(const bf16x8*)(vbase + (size_t)l16 * N_PIX + m0 + 32 + quad * 8);
        bf16x8 av1h = *(const bf16x8*)(vbase + (size_t)(16 + l16) * N_PIX + m0 + 32 + quad * 8);

        f32x4 st[4];
        f32x4 z = {0.f, 0.f, 0.f, 0.f};
        st[0] = mfma16(ak0, aq, z);
        st[1] = mfma16(ak1, aq, z);
        st[2] = mfma16(ak2, aq, z);
        st[3] = mfma16(ak3, aq, z);

        // P^T[m][n] = exp2(s*tl - B); pack 4 consecutive m -> b64 LDS write (chunked layout)
        for (int mt = 0; mt < 4; ++mt) {
            bf16x4 pk;
            for (int r = 0; r < 4; ++r)
                pk[r] = (bf16)fast_exp2(__builtin_fmaf(st[mt][r], tl, -Bb));
            int chunk = mt * 2 + (quad >> 1);
            *(bf16x4*)(pw + (chunk * 16 + l16) * 8 + (quad & 1) * 4) = pk;
        }
        // B-operand reads: lane(q,l) gets P^T[m=kc*32+q*8..+7][n=l], contiguous per lane
        bf16x8 ap0 = *(const bf16x8*)(pw + ((0 * 4 + quad) * 16 + l16) * 8);
        bf16x8 ap1 = *(const bf16x8*)(pw + ((1 * 4 + quad) * 16 + l16) * 8);

        o0 = mfma16(av0l, ap0, o0);
        o1 = mfma16(av0h, ap0, o1);
        o0 = mfma16(av1l, ap1, o0);
        o1 = mfma16(av1h, ap1, o1);
    }

    // epilogue: lane(q,l) holds O^T[d=q*4+r][n=l] (o0), [d=16+q*4+r] (o1); d=24 row = l
    int n = nbase + l16;
    size_t rowo = ((size_t)(split * 8 + head) * N_PIX + n) * 24;
    bf16x4 w0;
    for (int r = 0; r < 4; ++r) w0[r] = (bf16)o0[r];
    *(bf16x4*)(opart + rowo + quad * 4) = w0;
    if (quad < 2) {
        bf16x4 w1;
        for (int r = 0; r < 4; ++r) w1[r] = (bf16)o1[r];
        *(bf16x4*)(opart + rowo + 16 + quad * 4) = w1;
    }
    if (quad == 2)
        lpart[(size_t)(split * 8 + head) * N_PIX + n] = o1[0];   // d = 24: sum of P
}

// ---------------- combine split-K partials -> outt[n][c] bf16 ----------------
__global__ __launch_bounds__(256) void combine(const bf16* __restrict__ opart,
                                               const float* __restrict__ lpart,
                                               bf16* __restrict__ outt) {
    int idx = blockIdx.x * 256 + threadIdx.x;   // 8*4096*24 exactly
    int dd = idx % 24;
    int rest = idx / 24;
    int n = rest & 4095;
    int h = rest >> 12;
    float o = 0.f, l = 0.f;
    for (int s = 0; s < NSPLIT; ++s) {
        o += (float)opart[((size_t)(s * 8 + h) * N_PIX + n) * 24 + dd];
        l += lpart[(size_t)(s * 8 + h) * N_PIX + n];
    }
    outt[n * C_DIM + h * DHEAD + dd] = (bf16)(o / l);
}

extern "C" void kernel_launch(void* const* d_in, const int* in_sizes, int n_in,
                              void* d_out, int out_size, void* d_ws, size_t ws_size,
                              hipStream_t stream) {
    const float* x     = (const float*)d_in[0];
    const float* gamma = (const float*)d_in[1];
    const float* beta  = (const float*)d_in[2];
    const float* wqkv  = (const float*)d_in[3];
    const float* wdw   = (const float*)d_in[4];
    const float* bdw   = (const float*)d_in[5];
    const float* wproj = (const float*)d_in[6];
    const float* temp  = (const float*)d_in[7];
    float* out = (float*)d_out;

    char* ws = (char*)d_ws;
    bf16* wqkv_b  = (bf16*)(ws + 0);          // 221184
    bf16* wproj_b = (bf16*)(ws + 221184);     // 73728
    bf16* xln     = (bf16*)(ws + 294912);     // 1572864
    bf16* qkv     = (bf16*)(ws + 1867776);    // 4718592
    bf16* opart   = (bf16*)(ws + 294912);     // 3*8*4096*24*2 = 4718592 (alias xln+qkv, both dead)
    bf16* qt      = (bf16*)(ws + 6586368);    // 2097152
    bf16* kt      = (bf16*)(ws + 8683520);    // 2097152
    bf16* vl      = (bf16*)(ws + 10780672);   // 2097152
    bf16* outt    = (bf16*)(ws + 12877824);   // 1572864
    float* lpart  = (float*)(ws + 14450688);  // 393216
    float* maxk2  = (float*)(ws + 14843904);  // 32

    prep_ln<<<688, 256, 0, stream>>>(x, gamma, beta, xln, wqkv, wproj, wqkv_b, wproj_b, maxk2);
    gemm192<<<dim3(64, 9), 256, 0, stream>>>(wqkv_b, xln, qkv);
    dwconv<<<24 * 64, 256, 0, stream>>>(qkv, wdw, bdw, qt, kt, vl, maxk2);
    flash_attn<<<NSPLIT * 512, 256, 0, stream>>>(qt, kt, vl, temp, maxk2, opart, lpart);
    combine<<<3072, 256, 0, stream>>>(opart, lpart, outt);
    gemm_proj<<<dim3(128, 3), 256, 0, stream>>>(wproj_b, outt, out, x);
}

// Round 5
// 151.939 us; speedup vs baseline: 1.3237x; 1.3237x over previous
//
#include <hip/hip_runtime.h>
#include <hip/hip_bf16.h>

// MDTA: LN -> 1x1 conv (QKV) -> dw3x3 -> spatial attention (N=4096, d=24, 8 heads) -> proj + residual
// Flash attention: fat waves (64 q/wave), S^T form, fixed-bound softmax, ones-row V row-sum,
// direct-L2 K/V reads (no staging, no barriers), split-K=4 with compile-time NITER.

typedef __bf16 bf16;
typedef __bf16 bf16x2 __attribute__((ext_vector_type(2)));
typedef __bf16 bf16x4 __attribute__((ext_vector_type(4)));
typedef __bf16 bf16x8 __attribute__((ext_vector_type(8)));
typedef float f32x4 __attribute__((ext_vector_type(4)));

#define C_DIM 192
#define N_PIX 4096
#define HEADS 8
#define DHEAD 24
#define DPAD 32
#define C3 576
#define NSPLIT 4

__device__ inline float fast_exp2(float x) {
#if __has_builtin(__builtin_amdgcn_exp2f)
    return __builtin_amdgcn_exp2f(x);
#else
    return exp2f(x);
#endif
}

__device__ inline f32x4 mfma16(bf16x8 a, bf16x8 b, f32x4 c) {
    return __builtin_amdgcn_mfma_f32_16x16x32_bf16(a, b, c, 0, 0, 0);
}

// ---------------- merged: LayerNorm (blocks 0..255) + weight prep (blocks 256..687) ----------------
__global__ __launch_bounds__(256) void prep_ln(const float* __restrict__ x,
                                               const float* __restrict__ gamma,
                                               const float* __restrict__ beta,
                                               bf16* __restrict__ xln_t,
                                               const float* __restrict__ wqkv,
                                               const float* __restrict__ wproj,
                                               bf16* __restrict__ wqkv_b,
                                               bf16* __restrict__ wproj_b,
                                               float* __restrict__ maxk2) {
    int b = blockIdx.x, t = threadIdx.x;
    if (b >= 256) {
        int idx = (b - 256) * 256 + t;
        if (idx < C3 * C_DIM) wqkv_b[idx] = (bf16)wqkv[idx];
        if (idx < C_DIM * C_DIM) wproj_b[idx] = (bf16)wproj[idx];
        if (b == 256 && t < 8) maxk2[t] = 0.0f;
        return;
    }
    __shared__ float sred[256], ssred[256];
    int pixg = t & 15, cg = t >> 4;          // 16 pixels x 16 channel-groups of 12
    int p = b * 16 + pixg;
    float v[12];
    float s = 0.f, ss = 0.f;
    for (int j = 0; j < 12; ++j) {
        float f = x[(cg * 12 + j) * N_PIX + p];
        v[j] = f; s += f; ss += f * f;
    }
    sred[t] = s; ssred[t] = ss;
    __syncthreads();
    float S = 0.f, SS = 0.f;
    for (int k = 0; k < 16; ++k) { S += sred[k * 16 + pixg]; SS += ssred[k * 16 + pixg]; }
    float mean = S * (1.0f / C_DIM);
    float var = SS * (1.0f / C_DIM) - mean * mean;
    float rstd = rsqrtf(var + 1e-5f);
    for (int g = 0; g < 3; ++g) {
        bf16x4 w;
        for (int j = 0; j < 4; ++j) {
            int c = cg * 12 + g * 4 + j;
            w[j] = (bf16)((v[g * 4 + j] - mean) * rstd * gamma[c] + beta[c]);
        }
        *(bf16x4*)(xln_t + p * C_DIM + cg * 12 + g * 4) = w;
    }
}

// ---------------- GEMM (64x64 tile): out[M,4096] = A[M,192] * BT[4096,192]^T -> bf16 ----------------
__global__ __launch_bounds__(256) void gemm192(const bf16* __restrict__ A,
                                               const bf16* __restrict__ BT,
                                               bf16* __restrict__ outb) {
    const int K = 192;
    int n0 = blockIdx.x * 64;
    int m0 = blockIdx.y * 64;
    int tid = threadIdx.x;
    int wave = tid >> 6, lane = tid & 63;
    int l16 = lane & 15, quad = lane >> 4;
    int wm = (wave >> 1) * 32, wn = (wave & 1) * 32;
    f32x4 acc[2][2] = {};
    for (int kk = 0; kk < K; kk += 32) {
        bf16x8 a0 = *(const bf16x8*)(A + (m0 + wm + l16) * K + kk + quad * 8);
        bf16x8 a1 = *(const bf16x8*)(A + (m0 + wm + 16 + l16) * K + kk + quad * 8);
        bf16x8 b0 = *(const bf16x8*)(BT + (n0 + wn + l16) * K + kk + quad * 8);
        bf16x8 b1 = *(const bf16x8*)(BT + (n0 + wn + 16 + l16) * K + kk + quad * 8);
        acc[0][0] = mfma16(a0, b0, acc[0][0]);
        acc[0][1] = mfma16(a0, b1, acc[0][1]);
        acc[1][0] = mfma16(a1, b0, acc[1][0]);
        acc[1][1] = mfma16(a1, b1, acc[1][1]);
    }
    for (int i = 0; i < 2; ++i)
        for (int j = 0; j < 2; ++j)
            for (int r = 0; r < 4; ++r) {
                int row = m0 + wm + i * 16 + quad * 4 + r;
                int col = n0 + wn + j * 16 + l16;
                outb[row * N_PIX + col] = (bf16)acc[i][j][r];
            }
}

// ---------------- proj GEMM (64m x 32n tile) + fp32 residual epilogue (prefetched) ----------------
__global__ __launch_bounds__(256) void gemm_proj(const bf16* __restrict__ A,
                                                 const bf16* __restrict__ BT,
                                                 float* __restrict__ outf,
                                                 const float* __restrict__ resid) {
    const int K = 192;
    int n0 = blockIdx.x * 32;
    int m0 = blockIdx.y * 64;
    int tid = threadIdx.x;
    int wave = tid >> 6, lane = tid & 63;
    int l16 = lane & 15, quad = lane >> 4;
    int mrow = m0 + wave * 16;
    // prefetch residual before the K-loop (8 independent loads, latency overlapped)
    float rv[8];
    for (int j = 0; j < 2; ++j)
        for (int r = 0; r < 4; ++r)
            rv[j * 4 + r] = resid[(size_t)(mrow + quad * 4 + r) * N_PIX + n0 + j * 16 + l16];
    f32x4 acc[2] = {};
    for (int kk = 0; kk < K; kk += 32) {
        bf16x8 a = *(const bf16x8*)(A + (mrow + l16) * K + kk + quad * 8);
        bf16x8 b0 = *(const bf16x8*)(BT + (n0 + l16) * K + kk + quad * 8);
        bf16x8 b1 = *(const bf16x8*)(BT + (n0 + 16 + l16) * K + kk + quad * 8);
        acc[0] = mfma16(a, b0, acc[0]);
        acc[1] = mfma16(a, b1, acc[1]);
    }
    for (int j = 0; j < 2; ++j)
        for (int r = 0; r < 4; ++r) {
            int row = mrow + quad * 4 + r;
            int col = n0 + j * 16 + l16;
            outf[(size_t)row * N_PIX + col] = acc[j][r] + rv[j * 4 + r];
        }
}

// ---------------- depthwise 3x3 + bias -> q/k [h][n][32-pad], v [h][32-pad][n] ----------------
__global__ __launch_bounds__(256) void dwconv(const bf16* __restrict__ qkv,
                                              const float* __restrict__ wdw,
                                              const float* __restrict__ bdw,
                                              bf16* __restrict__ qt,
                                              bf16* __restrict__ kt,
                                              bf16* __restrict__ vl,
                                              float* __restrict__ maxk2) {
    __shared__ float k2s[4][64];
    int bh = blockIdx.x >> 6;              // 0..23 = part*8 + h
    int y = blockIdx.x & 63;
    int part = bh >> 3, h = bh & 7;
    int cg = threadIdx.x >> 6, px = threadIdx.x & 63;
    int p = y * 64 + px;
    int ch0 = part * C_DIM + h * DHEAD + cg * 6;

    float acc[6];
    for (int j = 0; j < 6; ++j) {
        int ch = ch0 + j;
        const bf16* in = qkv + ch * N_PIX;
        const float* w = wdw + ch * 9;
        float a = bdw[ch];
        for (int dy = -1; dy <= 1; ++dy) {
            int yy = y + dy;
            if (yy < 0 || yy > 63) continue;
            for (int dx = -1; dx <= 1; ++dx) {
                int xc = px + dx;
                if (xc < 0 || xc > 63) continue;
                a += w[(dy + 1) * 3 + (dx + 1)] * (float)in[yy * 64 + xc];
            }
        }
        acc[j] = a;
    }

    if (part < 2) {
        bf16* base = (part == 0 ? qt : kt) + ((size_t)(h * N_PIX + p)) * DPAD;
        bf16* dst = base + cg * 6;
        for (int g = 0; g < 3; ++g) {
            bf16x2 w2; w2[0] = (bf16)acc[g * 2]; w2[1] = (bf16)acc[g * 2 + 1];
            *(bf16x2*)(dst + g * 2) = w2;
        }
        if (cg == 3) {
            bf16x8 z;
            for (int j = 0; j < 8; ++j) z[j] = (bf16)0.0f;
            *(bf16x8*)(base + 24) = z;
        }
        if (part == 1) {
            float s2 = 0.f;
            for (int j = 0; j < 6; ++j) s2 += acc[j] * acc[j];
            k2s[cg][px] = s2;
        }
        __syncthreads();
        if (part == 1 && cg == 0) {
            float tot = k2s[0][px] + k2s[1][px] + k2s[2][px] + k2s[3][px];
            for (int off = 1; off < 64; off <<= 1)
                tot = fmaxf(tot, __shfl_xor(tot, off, 64));
            if (px == 0) atomicMax((unsigned int*)(maxk2 + h), __float_as_uint(tot));
        }
    } else {
        __syncthreads();
        for (int j = 0; j < 6; ++j)
            vl[((size_t)(h * DPAD + cg * 6 + j)) * N_PIX + p] = (bf16)acc[j];
        if (cg == 0) vl[((size_t)(h * DPAD + 24)) * N_PIX + p] = (bf16)1.0f;
        vl[((size_t)(h * DPAD + 25 + cg)) * N_PIX + p] = (bf16)0.0f;
        if (cg < 3) vl[((size_t)(h * DPAD + 29 + cg)) * N_PIX + p] = (bf16)0.0f;
    }
}

// ---------------- flash attention: fat waves (64 q/wave), no barriers, split-K=4 ----------------
// Wave owns 64 queries (4 B-fragments). Per key-tile (64 keys):
//   8 global b128 loads (K,V frags, L2-resident, shared across the 4 q-frags)
//   16 S^T MFMAs -> exp2 -> pack -> private-LDS P (per-f 2KB regions, no WAR hazard)
//   16 O^T MFMAs (V row 24 = ones gives row-sum free).
__global__ __launch_bounds__(256, 2) void flash_attn(const bf16* __restrict__ qt,
                                                     const bf16* __restrict__ kt,
                                                     const bf16* __restrict__ vl,
                                                     const float* __restrict__ temp,
                                                     const float* __restrict__ maxk2,
                                                     bf16* __restrict__ opart,
                                                     bf16* __restrict__ lpart) {
    __shared__ __align__(16) bf16 Plds[4 * 4096];   // 8KB per wave: [f(4)][chunk(8)][l16(16)][8]

    int tid = threadIdx.x;
    int wave = tid >> 6, lane = tid & 63;
    int l16 = lane & 15, quad = lane >> 4;
    int head = blockIdx.x & 7;               // block -> XCD is round-robin: head pinned per XCD
    int qb = (blockIdx.x >> 3) & 15;
    int split = blockIdx.x >> 7;             // 0..3
    int nbase = qb * 256 + wave * 64;
    float tl = temp[head] * 1.44269504f;

    // Q fragments (B-operand): B[n = f*16+l16][k = quad*8+j]
    const bf16* qrow = qt + ((size_t)head * N_PIX + nbase) * DPAD;
    bf16x8 aq[4];
    for (int f = 0; f < 4; ++f)
        aq[f] = *(const bf16x8*)(qrow + (size_t)(f * 16 + l16) * DPAD + quad * 8);

    // per-(f,lane) bound: B = |tl| * ||q_n|| * max||k|| + 1
    float mk2 = maxk2[head];
    float Bb[4];
    for (int f = 0; f < 4; ++f) {
        float q2 = 0.f;
        for (int j = 0; j < 8; ++j) { float v = (float)aq[f][j]; q2 += v * v; }
        q2 += __shfl_xor(q2, 16, 64);
        q2 += __shfl_xor(q2, 32, 64);
        Bb[f] = fabsf(tl) * sqrtf(q2 * mk2) + 1.0f;
    }

    const bf16* kbase = kt + (size_t)head * N_PIX * DPAD;
    const bf16* vbase = vl + (size_t)head * DPAD * N_PIX;
    bf16* pw = Plds + wave * 4096;

    f32x4 o0[4] = {}, o1[4] = {};

    #pragma unroll 2
    for (int it = 0; it < 16; ++it) {
        int m0 = (split * 16 + it) * 64;
        // K fragments (A-operand): rows m, k = d
        bf16x8 ak[4];
        for (int mt = 0; mt < 4; ++mt)
            ak[mt] = *(const bf16x8*)(kbase + (size_t)(m0 + mt * 16 + l16) * DPAD + quad * 8);
        // V fragments (A-operand): rows d (0..31), k = m
        bf16x8 av[4];
        av[0] = *(const bf16x8*)(vbase + (size_t)l16 * N_PIX + m0 + quad * 8);
        av[1] = *(const bf16x8*)(vbase + (size_t)(16 + l16) * N_PIX + m0 + quad * 8);
        av[2] = *(const bf16x8*)(vbase + (size_t)l16 * N_PIX + m0 + 32 + quad * 8);
        av[3] = *(const bf16x8*)(vbase + (size_t)(16 + l16) * N_PIX + m0 + 32 + quad * 8);

        // S^T + P for each q-fragment
        for (int f = 0; f < 4; ++f) {
            f32x4 z = {0.f, 0.f, 0.f, 0.f};
            f32x4 st[4];
            for (int mt = 0; mt < 4; ++mt) st[mt] = mfma16(ak[mt], aq[f], z);
            for (int mt = 0; mt < 4; ++mt) {
                bf16x4 pk;
                for (int r = 0; r < 4; ++r)
                    pk[r] = (bf16)fast_exp2(__builtin_fmaf(st[mt][r], tl, -Bb[f]));
                int chunk = mt * 2 + (quad >> 1);
                *(bf16x4*)(pw + f * 1024 + (chunk * 16 + l16) * 8 + (quad & 1) * 4) = pk;
            }
        }
        // O^T accumulate
        for (int f = 0; f < 4; ++f) {
            bf16x8 ap0 = *(const bf16x8*)(pw + f * 1024 + (quad * 16 + l16) * 8);
            bf16x8 ap1 = *(const bf16x8*)(pw + f * 1024 + ((4 + quad) * 16 + l16) * 8);
            o0[f] = mfma16(av[0], ap0, o0[f]);
            o1[f] = mfma16(av[1], ap0, o1[f]);
            o0[f] = mfma16(av[2], ap1, o0[f]);
            o1[f] = mfma16(av[3], ap1, o1[f]);
        }
    }

    // epilogue: lane holds O^T[d=quad*4+r][n=f*16+l16] (o0), [d=16+quad*4+r] (o1); d=24 = P row-sum
    for (int f = 0; f < 4; ++f) {
        int n = nbase + f * 16 + l16;
        size_t rowo = ((size_t)(split * 8 + head) * N_PIX + n) * 24;
        bf16x4 w0;
        for (int r = 0; r < 4; ++r) w0[r] = (bf16)o0[f][r];
        *(bf16x4*)(opart + rowo + quad * 4) = w0;
        if (quad < 2) {
            bf16x4 w1;
            for (int r = 0; r < 4; ++r) w1[r] = (bf16)o1[f][r];
            *(bf16x4*)(opart + rowo + 16 + quad * 4) = w1;
        }
        if (quad == 2)
            lpart[(size_t)(split * 8 + head) * N_PIX + n] = (bf16)o1[f][0];
    }
}

// ---------------- combine split-K partials -> outt[n][c] bf16 (coalesced rows) ----------------
__global__ __launch_bounds__(256) void combine(const bf16* __restrict__ opart,
                                               const bf16* __restrict__ lpart,
                                               bf16* __restrict__ outt) {
    int idx = blockIdx.x * 256 + threadIdx.x;   // 8*4096 threads, one (h,n) row each
    int n = idx & 4095;
    int h = idx >> 12;
    float acc[24];
    for (int j = 0; j < 24; ++j) acc[j] = 0.f;
    float l = 0.f;
    for (int s = 0; s < NSPLIT; ++s) {
        const bf16* row = opart + ((size_t)(s * 8 + h) * N_PIX + n) * 24;
        bf16x8 a = *(const bf16x8*)(row);
        bf16x8 b = *(const bf16x8*)(row + 8);
        bf16x8 c = *(const bf16x8*)(row + 16);
        for (int j = 0; j < 8; ++j) {
            acc[j] += (float)a[j];
            acc[8 + j] += (float)b[j];
            acc[16 + j] += (float)c[j];
        }
        l += (float)lpart[(size_t)(s * 8 + h) * N_PIX + n];
    }
    float inv = 1.0f / l;
    bf16* dst = outt + (size_t)n * C_DIM + h * DHEAD;
    for (int g = 0; g < 3; ++g) {
        bf16x8 w;
        for (int j = 0; j < 8; ++j) w[j] = (bf16)(acc[g * 8 + j] * inv);
        *(bf16x8*)(dst + g * 8) = w;
    }
}

extern "C" void kernel_launch(void* const* d_in, const int* in_sizes, int n_in,
                              void* d_out, int out_size, void* d_ws, size_t ws_size,
                              hipStream_t stream) {
    const float* x     = (const float*)d_in[0];
    const float* gamma = (const float*)d_in[1];
    const float* beta  = (const float*)d_in[2];
    const float* wqkv  = (const float*)d_in[3];
    const float* wdw   = (const float*)d_in[4];
    const float* bdw   = (const float*)d_in[5];
    const float* wproj = (const float*)d_in[6];
    const float* temp  = (const float*)d_in[7];
    float* out = (float*)d_out;

    char* ws = (char*)d_ws;
    bf16* wqkv_b  = (bf16*)(ws + 0);          // 221184
    bf16* wproj_b = (bf16*)(ws + 221184);     // 73728
    bf16* xln     = (bf16*)(ws + 294912);     // 1572864
    bf16* qkv     = (bf16*)(ws + 1867776);    // 4718592
    bf16* opart   = (bf16*)(ws + 294912);     // 4*8*4096*24*2 = 6291456 (alias xln+qkv, both dead)
    bf16* qt      = (bf16*)(ws + 6586368);    // 2097152  (reused as outt after flash)
    bf16* kt      = (bf16*)(ws + 8683520);    // 2097152
    bf16* vl      = (bf16*)(ws + 10780672);   // 2097152
    bf16* outt    = (bf16*)(ws + 6586368);    // = qt region, dead after flash
    bf16* lpart   = (bf16*)(ws + 14450688);   // 4*8*4096*2 = 262144
    float* maxk2  = (float*)(ws + 14843904);  // 32

    prep_ln<<<688, 256, 0, stream>>>(x, gamma, beta, xln, wqkv, wproj, wqkv_b, wproj_b, maxk2);
    gemm192<<<dim3(64, 9), 256, 0, stream>>>(wqkv_b, xln, qkv);
    dwconv<<<24 * 64, 256, 0, stream>>>(qkv, wdw, bdw, qt, kt, vl, maxk2);
    flash_attn<<<NSPLIT * 128, 256, 0, stream>>>(qt, kt, vl, temp, maxk2, opart, lpart);
    combine<<<128, 256, 0, stream>>>(opart, lpart, outt);
    gemm_proj<<<dim3(128, 3), 256, 0, stream>>>(wproj_b, outt, out, x);
}

// Round 6
// 147.530 us; speedup vs baseline: 1.3632x; 1.0299x over previous
//
#include <hip/hip_runtime.h>
#include <hip/hip_bf16.h>

// MDTA: LN -> 1x1 conv (QKV) -> dw3x3 -> spatial attention (N=4096, d=24, 8 heads) -> proj + residual
// Flash attention: fat waves (64 q/wave), S^T form, fixed-bound softmax, ones-row V row-sum,
// direct-L2 K/V reads (no staging, no barriers), split-K=8 (4 blocks/CU, 16 waves/CU).

typedef __bf16 bf16;
typedef __bf16 bf16x2 __attribute__((ext_vector_type(2)));
typedef __bf16 bf16x4 __attribute__((ext_vector_type(4)));
typedef __bf16 bf16x8 __attribute__((ext_vector_type(8)));
typedef float f32x4 __attribute__((ext_vector_type(4)));

#define C_DIM 192
#define N_PIX 4096
#define HEADS 8
#define DHEAD 24
#define DPAD 32
#define C3 576
#define NSPLIT 8

__device__ inline float fast_exp2(float x) {
#if __has_builtin(__builtin_amdgcn_exp2f)
    return __builtin_amdgcn_exp2f(x);
#else
    return exp2f(x);
#endif
}

__device__ inline f32x4 mfma16(bf16x8 a, bf16x8 b, f32x4 c) {
    return __builtin_amdgcn_mfma_f32_16x16x32_bf16(a, b, c, 0, 0, 0);
}

// ---------------- merged: LayerNorm (blocks 0..255) + weight prep (blocks 256..687) ----------------
__global__ __launch_bounds__(256) void prep_ln(const float* __restrict__ x,
                                               const float* __restrict__ gamma,
                                               const float* __restrict__ beta,
                                               bf16* __restrict__ xln_t,
                                               const float* __restrict__ wqkv,
                                               const float* __restrict__ wproj,
                                               bf16* __restrict__ wqkv_b,
                                               bf16* __restrict__ wproj_b,
                                               float* __restrict__ maxk2) {
    int b = blockIdx.x, t = threadIdx.x;
    if (b >= 256) {
        int idx = (b - 256) * 256 + t;
        if (idx < C3 * C_DIM) wqkv_b[idx] = (bf16)wqkv[idx];
        if (idx < C_DIM * C_DIM) wproj_b[idx] = (bf16)wproj[idx];
        if (b == 256 && t < 8) maxk2[t] = 0.0f;
        return;
    }
    __shared__ float sred[256], ssred[256];
    int pixg = t & 15, cg = t >> 4;          // 16 pixels x 16 channel-groups of 12
    int p = b * 16 + pixg;
    float v[12];
    float s = 0.f, ss = 0.f;
    for (int j = 0; j < 12; ++j) {
        float f = x[(cg * 12 + j) * N_PIX + p];
        v[j] = f; s += f; ss += f * f;
    }
    sred[t] = s; ssred[t] = ss;
    __syncthreads();
    float S = 0.f, SS = 0.f;
    for (int k = 0; k < 16; ++k) { S += sred[k * 16 + pixg]; SS += ssred[k * 16 + pixg]; }
    float mean = S * (1.0f / C_DIM);
    float var = SS * (1.0f / C_DIM) - mean * mean;
    float rstd = rsqrtf(var + 1e-5f);
    for (int g = 0; g < 3; ++g) {
        bf16x4 w;
        for (int j = 0; j < 4; ++j) {
            int c = cg * 12 + g * 4 + j;
            w[j] = (bf16)((v[g * 4 + j] - mean) * rstd * gamma[c] + beta[c]);
        }
        *(bf16x4*)(xln_t + p * C_DIM + cg * 12 + g * 4) = w;
    }
}

// ---------------- GEMM (64x64 tile): out[M,4096] = A[M,192] * BT[4096,192]^T -> bf16 ----------------
__global__ __launch_bounds__(256) void gemm192(const bf16* __restrict__ A,
                                               const bf16* __restrict__ BT,
                                               bf16* __restrict__ outb) {
    const int K = 192;
    int n0 = blockIdx.x * 64;
    int m0 = blockIdx.y * 64;
    int tid = threadIdx.x;
    int wave = tid >> 6, lane = tid & 63;
    int l16 = lane & 15, quad = lane >> 4;
    int wm = (wave >> 1) * 32, wn = (wave & 1) * 32;
    f32x4 acc[2][2] = {};
    for (int kk = 0; kk < K; kk += 32) {
        bf16x8 a0 = *(const bf16x8*)(A + (m0 + wm + l16) * K + kk + quad * 8);
        bf16x8 a1 = *(const bf16x8*)(A + (m0 + wm + 16 + l16) * K + kk + quad * 8);
        bf16x8 b0 = *(const bf16x8*)(BT + (n0 + wn + l16) * K + kk + quad * 8);
        bf16x8 b1 = *(const bf16x8*)(BT + (n0 + wn + 16 + l16) * K + kk + quad * 8);
        acc[0][0] = mfma16(a0, b0, acc[0][0]);
        acc[0][1] = mfma16(a0, b1, acc[0][1]);
        acc[1][0] = mfma16(a1, b0, acc[1][0]);
        acc[1][1] = mfma16(a1, b1, acc[1][1]);
    }
    for (int i = 0; i < 2; ++i)
        for (int j = 0; j < 2; ++j)
            for (int r = 0; r < 4; ++r) {
                int row = m0 + wm + i * 16 + quad * 4 + r;
                int col = n0 + wn + j * 16 + l16;
                outb[row * N_PIX + col] = (bf16)acc[i][j][r];
            }
}

// ---------------- proj GEMM (64m x 32n tile) + fp32 residual epilogue (prefetched) ----------------
__global__ __launch_bounds__(256) void gemm_proj(const bf16* __restrict__ A,
                                                 const bf16* __restrict__ BT,
                                                 float* __restrict__ outf,
                                                 const float* __restrict__ resid) {
    const int K = 192;
    int n0 = blockIdx.x * 32;
    int m0 = blockIdx.y * 64;
    int tid = threadIdx.x;
    int wave = tid >> 6, lane = tid & 63;
    int l16 = lane & 15, quad = lane >> 4;
    int mrow = m0 + wave * 16;
    float rv[8];
    for (int j = 0; j < 2; ++j)
        for (int r = 0; r < 4; ++r)
            rv[j * 4 + r] = resid[(size_t)(mrow + quad * 4 + r) * N_PIX + n0 + j * 16 + l16];
    f32x4 acc[2] = {};
    for (int kk = 0; kk < K; kk += 32) {
        bf16x8 a = *(const bf16x8*)(A + (mrow + l16) * K + kk + quad * 8);
        bf16x8 b0 = *(const bf16x8*)(BT + (n0 + l16) * K + kk + quad * 8);
        bf16x8 b1 = *(const bf16x8*)(BT + (n0 + 16 + l16) * K + kk + quad * 8);
        acc[0] = mfma16(a, b0, acc[0]);
        acc[1] = mfma16(a, b1, acc[1]);
    }
    for (int j = 0; j < 2; ++j)
        for (int r = 0; r < 4; ++r) {
            int row = mrow + quad * 4 + r;
            int col = n0 + j * 16 + l16;
            outf[(size_t)row * N_PIX + col] = acc[j][r] + rv[j * 4 + r];
        }
}

// ---------------- depthwise 3x3 + bias -> q/k [h][n][32-pad], v [h][32-pad][n] ----------------
__global__ __launch_bounds__(256) void dwconv(const bf16* __restrict__ qkv,
                                              const float* __restrict__ wdw,
                                              const float* __restrict__ bdw,
                                              bf16* __restrict__ qt,
                                              bf16* __restrict__ kt,
                                              bf16* __restrict__ vl,
                                              float* __restrict__ maxk2) {
    __shared__ float k2s[4][64];
    int bh = blockIdx.x >> 6;              // 0..23 = part*8 + h
    int y = blockIdx.x & 63;
    int part = bh >> 3, h = bh & 7;
    int cg = threadIdx.x >> 6, px = threadIdx.x & 63;
    int p = y * 64 + px;
    int ch0 = part * C_DIM + h * DHEAD + cg * 6;

    float acc[6];
    for (int j = 0; j < 6; ++j) {
        int ch = ch0 + j;
        const bf16* in = qkv + ch * N_PIX;
        const float* w = wdw + ch * 9;
        float a = bdw[ch];
        for (int dy = -1; dy <= 1; ++dy) {
            int yy = y + dy;
            if (yy < 0 || yy > 63) continue;
            for (int dx = -1; dx <= 1; ++dx) {
                int xc = px + dx;
                if (xc < 0 || xc > 63) continue;
                a += w[(dy + 1) * 3 + (dx + 1)] * (float)in[yy * 64 + xc];
            }
        }
        acc[j] = a;
    }

    if (part < 2) {
        bf16* base = (part == 0 ? qt : kt) + ((size_t)(h * N_PIX + p)) * DPAD;
        bf16* dst = base + cg * 6;
        for (int g = 0; g < 3; ++g) {
            bf16x2 w2; w2[0] = (bf16)acc[g * 2]; w2[1] = (bf16)acc[g * 2 + 1];
            *(bf16x2*)(dst + g * 2) = w2;
        }
        if (cg == 3) {
            bf16x8 z;
            for (int j = 0; j < 8; ++j) z[j] = (bf16)0.0f;
            *(bf16x8*)(base + 24) = z;
        }
        if (part == 1) {
            float s2 = 0.f;
            for (int j = 0; j < 6; ++j) s2 += acc[j] * acc[j];
            k2s[cg][px] = s2;
        }
        __syncthreads();
        if (part == 1 && cg == 0) {
            float tot = k2s[0][px] + k2s[1][px] + k2s[2][px] + k2s[3][px];
            for (int off = 1; off < 64; off <<= 1)
                tot = fmaxf(tot, __shfl_xor(tot, off, 64));
            if (px == 0) atomicMax((unsigned int*)(maxk2 + h), __float_as_uint(tot));
        }
    } else {
        __syncthreads();
        for (int j = 0; j < 6; ++j)
            vl[((size_t)(h * DPAD + cg * 6 + j)) * N_PIX + p] = (bf16)acc[j];
        if (cg == 0) vl[((size_t)(h * DPAD + 24)) * N_PIX + p] = (bf16)1.0f;
        vl[((size_t)(h * DPAD + 25 + cg)) * N_PIX + p] = (bf16)0.0f;
        if (cg < 3) vl[((size_t)(h * DPAD + 29 + cg)) * N_PIX + p] = (bf16)0.0f;
    }
}

// ---------------- flash attention: fat waves (64 q/wave), no barriers, split-K=8 ----------------
// Wave owns 64 queries (4 B-fragments). Per key-tile (64 keys):
//   8 global b128 loads (K,V frags, L2-resident, shared across the 4 q-frags)
//   16 S^T MFMAs -> exp2 -> pack -> private-LDS P (per-f 2KB regions, no WAR hazard)
//   16 O^T MFMAs (V row 24 = ones gives row-sum free).
// Grid 1024 = 4 blocks/CU = 16 waves/CU; launch_bounds(256,4) pins VGPR <= 128.
__global__ __launch_bounds__(256, 4) void flash_attn(const bf16* __restrict__ qt,
                                                     const bf16* __restrict__ kt,
                                                     const bf16* __restrict__ vl,
                                                     const float* __restrict__ temp,
                                                     const float* __restrict__ maxk2,
                                                     bf16* __restrict__ opart,
                                                     bf16* __restrict__ lpart) {
    __shared__ __align__(16) bf16 Plds[4 * 4096];   // 8KB per wave: [f(4)][chunk(8)][l16(16)][8]

    int tid = threadIdx.x;
    int wave = tid >> 6, lane = tid & 63;
    int l16 = lane & 15, quad = lane >> 4;
    int head = blockIdx.x & 7;               // block -> XCD round-robin: head pinned per XCD
    int qb = (blockIdx.x >> 3) & 15;
    int split = blockIdx.x >> 7;             // 0..7
    int nbase = qb * 256 + wave * 64;
    float tl = temp[head] * 1.44269504f;

    // Q fragments (B-operand): B[n = f*16+l16][k = quad*8+j]
    const bf16* qrow = qt + ((size_t)head * N_PIX + nbase) * DPAD;
    bf16x8 aq[4];
    for (int f = 0; f < 4; ++f)
        aq[f] = *(const bf16x8*)(qrow + (size_t)(f * 16 + l16) * DPAD + quad * 8);

    // per-(f,lane) bound: B = |tl| * ||q_n|| * max||k|| + 1
    float mk2 = maxk2[head];
    float Bb[4];
    for (int f = 0; f < 4; ++f) {
        float q2 = 0.f;
        for (int j = 0; j < 8; ++j) { float v = (float)aq[f][j]; q2 += v * v; }
        q2 += __shfl_xor(q2, 16, 64);
        q2 += __shfl_xor(q2, 32, 64);
        Bb[f] = fabsf(tl) * sqrtf(q2 * mk2) + 1.0f;
    }

    const bf16* kbase = kt + (size_t)head * N_PIX * DPAD;
    const bf16* vbase = vl + (size_t)head * DPAD * N_PIX;
    bf16* pw = Plds + wave * 4096;

    f32x4 o0[4] = {}, o1[4] = {};

    #pragma unroll 2
    for (int it = 0; it < 64 / NSPLIT; ++it) {
        int m0 = (split * (64 / NSPLIT) + it) * 64;
        // K fragments (A-operand): rows m, k = d
        bf16x8 ak[4];
        for (int mt = 0; mt < 4; ++mt)
            ak[mt] = *(const bf16x8*)(kbase + (size_t)(m0 + mt * 16 + l16) * DPAD + quad * 8);
        // V fragments (A-operand): rows d (0..31), k = m
        bf16x8 av[4];
        av[0] = *(const bf16x8*)(vbase + (size_t)l16 * N_PIX + m0 + quad * 8);
        av[1] = *(const bf16x8*)(vbase + (size_t)(16 + l16) * N_PIX + m0 + quad * 8);
        av[2] = *(const bf16x8*)(vbase + (size_t)l16 * N_PIX + m0 + 32 + quad * 8);
        av[3] = *(const bf16x8*)(vbase + (size_t)(16 + l16) * N_PIX + m0 + 32 + quad * 8);

        // S^T + P for each q-fragment
        for (int f = 0; f < 4; ++f) {
            f32x4 z = {0.f, 0.f, 0.f, 0.f};
            f32x4 st[4];
            for (int mt = 0; mt < 4; ++mt) st[mt] = mfma16(ak[mt], aq[f], z);
            for (int mt = 0; mt < 4; ++mt) {
                bf16x4 pk;
                for (int r = 0; r < 4; ++r)
                    pk[r] = (bf16)fast_exp2(__builtin_fmaf(st[mt][r], tl, -Bb[f]));
                int chunk = mt * 2 + (quad >> 1);
                *(bf16x4*)(pw + f * 1024 + (chunk * 16 + l16) * 8 + (quad & 1) * 4) = pk;
            }
        }
        // O^T accumulate
        for (int f = 0; f < 4; ++f) {
            bf16x8 ap0 = *(const bf16x8*)(pw + f * 1024 + (quad * 16 + l16) * 8);
            bf16x8 ap1 = *(const bf16x8*)(pw + f * 1024 + ((4 + quad) * 16 + l16) * 8);
            o0[f] = mfma16(av[0], ap0, o0[f]);
            o1[f] = mfma16(av[1], ap0, o1[f]);
            o0[f] = mfma16(av[2], ap1, o0[f]);
            o1[f] = mfma16(av[3], ap1, o1[f]);
        }
    }

    // epilogue: lane holds O^T[d=quad*4+r][n=f*16+l16] (o0), [d=16+quad*4+r] (o1); d=24 = P row-sum
    for (int f = 0; f < 4; ++f) {
        int n = nbase + f * 16 + l16;
        size_t rowo = ((size_t)(split * 8 + head) * N_PIX + n) * 24;
        bf16x4 w0;
        for (int r = 0; r < 4; ++r) w0[r] = (bf16)o0[f][r];
        *(bf16x4*)(opart + rowo + quad * 4) = w0;
        if (quad < 2) {
            bf16x4 w1;
            for (int r = 0; r < 4; ++r) w1[r] = (bf16)o1[f][r];
            *(bf16x4*)(opart + rowo + 16 + quad * 4) = w1;
        }
        if (quad == 2)
            lpart[(size_t)(split * 8 + head) * N_PIX + n] = (bf16)o1[f][0];
    }
}

// ---------------- combine split-K partials -> outt[n][c] bf16 (coalesced rows) ----------------
__global__ __launch_bounds__(256) void combine(const bf16* __restrict__ opart,
                                               const bf16* __restrict__ lpart,
                                               bf16* __restrict__ outt) {
    int idx = blockIdx.x * 256 + threadIdx.x;   // 8*4096 threads, one (h,n) row each
    int n = idx & 4095;
    int h = idx >> 12;
    float acc[24];
    for (int j = 0; j < 24; ++j) acc[j] = 0.f;
    float l = 0.f;
    for (int s = 0; s < NSPLIT; ++s) {
        const bf16* row = opart + ((size_t)(s * 8 + h) * N_PIX + n) * 24;
        bf16x8 a = *(const bf16x8*)(row);
        bf16x8 b = *(const bf16x8*)(row + 8);
        bf16x8 c = *(const bf16x8*)(row + 16);
        for (int j = 0; j < 8; ++j) {
            acc[j] += (float)a[j];
            acc[8 + j] += (float)b[j];
            acc[16 + j] += (float)c[j];
        }
        l += (float)lpart[(size_t)(s * 8 + h) * N_PIX + n];
    }
    float inv = 1.0f / l;
    bf16* dst = outt + (size_t)n * C_DIM + h * DHEAD;
    for (int g = 0; g < 3; ++g) {
        bf16x8 w;
        for (int j = 0; j < 8; ++j) w[j] = (bf16)(acc[g * 8 + j] * inv);
        *(bf16x8*)(dst + g * 8) = w;
    }
}

extern "C" void kernel_launch(void* const* d_in, const int* in_sizes, int n_in,
                              void* d_out, int out_size, void* d_ws, size_t ws_size,
                              hipStream_t stream) {
    const float* x     = (const float*)d_in[0];
    const float* gamma = (const float*)d_in[1];
    const float* beta  = (const float*)d_in[2];
    const float* wqkv  = (const float*)d_in[3];
    const float* wdw   = (const float*)d_in[4];
    const float* bdw   = (const float*)d_in[5];
    const float* wproj = (const float*)d_in[6];
    const float* temp  = (const float*)d_in[7];
    float* out = (float*)d_out;

    // workspace (ws_size is 256 MiB per harness poison traffic) — no aliasing needed
    char* ws = (char*)d_ws;
    bf16* wqkv_b  = (bf16*)(ws + 0);          // 221184
    bf16* wproj_b = (bf16*)(ws + 221184);     // 73728
    bf16* xln     = (bf16*)(ws + 294912);     // 1572864  (-> 1867776)
    bf16* qkv     = (bf16*)(ws + 1867776);    // 4718592  (-> 6586368)
    bf16* qt      = (bf16*)(ws + 6586368);    // 2097152  (-> 8683520; reused as outt after flash)
    bf16* kt      = (bf16*)(ws + 8683520);    // 2097152  (-> 10780672)
    bf16* vl      = (bf16*)(ws + 10780672);   // 2097152  (-> 12877824)
    bf16* opart   = (bf16*)(ws + 12877824);   // 8*8*4096*24*2 = 12582912 (-> 25460736)
    bf16* lpart   = (bf16*)(ws + 25460736);   // 8*8*4096*2 = 524288     (-> 25985024)
    float* maxk2  = (float*)(ws + 25985024);  // 32
    bf16* outt    = qt;                       // qt dead after flash

    prep_ln<<<688, 256, 0, stream>>>(x, gamma, beta, xln, wqkv, wproj, wqkv_b, wproj_b, maxk2);
    gemm192<<<dim3(64, 9), 256, 0, stream>>>(wqkv_b, xln, qkv);
    dwconv<<<24 * 64, 256, 0, stream>>>(qkv, wdw, bdw, qt, kt, vl, maxk2);
    flash_attn<<<NSPLIT * 128, 256, 0, stream>>>(qt, kt, vl, temp, maxk2, opart, lpart);
    combine<<<128, 256, 0, stream>>>(opart, lpart, outt);
    gemm_proj<<<dim3(128, 3), 256, 0, stream>>>(wproj_b, outt, out, x);
}

// Round 7
// 139.279 us; speedup vs baseline: 1.4440x; 1.0592x over previous
//
#include <hip/hip_runtime.h>
#include <hip/hip_bf16.h>

// MDTA: LN -> 1x1 conv (QKV) -> dw3x3 -> spatial attention (N=4096, d=24, 8 heads) -> proj + residual
// Flash attention: fat waves (64 q/wave), S^T form, fixed-bound softmax, ones-row V row-sum,
// direct-L2 K/V reads, split-K=8. This round: vectorized dwconv (3 vector loads vs 54 scalar).

typedef __bf16 bf16;
typedef __bf16 bf16x2 __attribute__((ext_vector_type(2)));
typedef __bf16 bf16x4 __attribute__((ext_vector_type(4)));
typedef __bf16 bf16x8 __attribute__((ext_vector_type(8)));
typedef float f32x4 __attribute__((ext_vector_type(4)));

#define C_DIM 192
#define N_PIX 4096
#define HEADS 8
#define DHEAD 24
#define DPAD 32
#define C3 576
#define NSPLIT 8

__device__ inline float fast_exp2(float x) {
#if __has_builtin(__builtin_amdgcn_exp2f)
    return __builtin_amdgcn_exp2f(x);
#else
    return exp2f(x);
#endif
}

__device__ inline f32x4 mfma16(bf16x8 a, bf16x8 b, f32x4 c) {
    return __builtin_amdgcn_mfma_f32_16x16x32_bf16(a, b, c, 0, 0, 0);
}

// ---------------- merged: LayerNorm (blocks 0..255) + weight prep (blocks 256..687) ----------------
__global__ __launch_bounds__(256) void prep_ln(const float* __restrict__ x,
                                               const float* __restrict__ gamma,
                                               const float* __restrict__ beta,
                                               bf16* __restrict__ xln_t,
                                               const float* __restrict__ wqkv,
                                               const float* __restrict__ wproj,
                                               bf16* __restrict__ wqkv_b,
                                               bf16* __restrict__ wproj_b,
                                               float* __restrict__ maxk2) {
    int b = blockIdx.x, t = threadIdx.x;
    if (b >= 256) {
        int idx = (b - 256) * 256 + t;
        if (idx < C3 * C_DIM) wqkv_b[idx] = (bf16)wqkv[idx];
        if (idx < C_DIM * C_DIM) wproj_b[idx] = (bf16)wproj[idx];
        if (b == 256 && t < 8) maxk2[t] = 0.0f;
        return;
    }
    __shared__ float sred[256], ssred[256];
    int pixg = t & 15, cg = t >> 4;          // 16 pixels x 16 channel-groups of 12
    int p = b * 16 + pixg;
    float v[12];
    float s = 0.f, ss = 0.f;
    for (int j = 0; j < 12; ++j) {
        float f = x[(cg * 12 + j) * N_PIX + p];
        v[j] = f; s += f; ss += f * f;
    }
    sred[t] = s; ssred[t] = ss;
    __syncthreads();
    float S = 0.f, SS = 0.f;
    for (int k = 0; k < 16; ++k) { S += sred[k * 16 + pixg]; SS += ssred[k * 16 + pixg]; }
    float mean = S * (1.0f / C_DIM);
    float var = SS * (1.0f / C_DIM) - mean * mean;
    float rstd = rsqrtf(var + 1e-5f);
    for (int g = 0; g < 3; ++g) {
        bf16x4 w;
        for (int j = 0; j < 4; ++j) {
            int c = cg * 12 + g * 4 + j;
            w[j] = (bf16)((v[g * 4 + j] - mean) * rstd * gamma[c] + beta[c]);
        }
        *(bf16x4*)(xln_t + p * C_DIM + cg * 12 + g * 4) = w;
    }
}

// ---------------- GEMM (64x64 tile): out[M,4096] = A[M,192] * BT[4096,192]^T -> bf16 ----------------
__global__ __launch_bounds__(256) void gemm192(const bf16* __restrict__ A,
                                               const bf16* __restrict__ BT,
                                               bf16* __restrict__ outb) {
    const int K = 192;
    int n0 = blockIdx.x * 64;
    int m0 = blockIdx.y * 64;
    int tid = threadIdx.x;
    int wave = tid >> 6, lane = tid & 63;
    int l16 = lane & 15, quad = lane >> 4;
    int wm = (wave >> 1) * 32, wn = (wave & 1) * 32;
    f32x4 acc[2][2] = {};
    for (int kk = 0; kk < K; kk += 32) {
        bf16x8 a0 = *(const bf16x8*)(A + (m0 + wm + l16) * K + kk + quad * 8);
        bf16x8 a1 = *(const bf16x8*)(A + (m0 + wm + 16 + l16) * K + kk + quad * 8);
        bf16x8 b0 = *(const bf16x8*)(BT + (n0 + wn + l16) * K + kk + quad * 8);
        bf16x8 b1 = *(const bf16x8*)(BT + (n0 + wn + 16 + l16) * K + kk + quad * 8);
        acc[0][0] = mfma16(a0, b0, acc[0][0]);
        acc[0][1] = mfma16(a0, b1, acc[0][1]);
        acc[1][0] = mfma16(a1, b0, acc[1][0]);
        acc[1][1] = mfma16(a1, b1, acc[1][1]);
    }
    for (int i = 0; i < 2; ++i)
        for (int j = 0; j < 2; ++j)
            for (int r = 0; r < 4; ++r) {
                int row = m0 + wm + i * 16 + quad * 4 + r;
                int col = n0 + wn + j * 16 + l16;
                outb[row * N_PIX + col] = (bf16)acc[i][j][r];
            }
}

// ---------------- proj GEMM (64m x 32n tile) + fp32 residual epilogue (prefetched) ----------------
__global__ __launch_bounds__(256) void gemm_proj(const bf16* __restrict__ A,
                                                 const bf16* __restrict__ BT,
                                                 float* __restrict__ outf,
                                                 const float* __restrict__ resid) {
    const int K = 192;
    int n0 = blockIdx.x * 32;
    int m0 = blockIdx.y * 64;
    int tid = threadIdx.x;
    int wave = tid >> 6, lane = tid & 63;
    int l16 = lane & 15, quad = lane >> 4;
    int mrow = m0 + wave * 16;
    float rv[8];
    for (int j = 0; j < 2; ++j)
        for (int r = 0; r < 4; ++r)
            rv[j * 4 + r] = resid[(size_t)(mrow + quad * 4 + r) * N_PIX + n0 + j * 16 + l16];
    f32x4 acc[2] = {};
    for (int kk = 0; kk < K; kk += 32) {
        bf16x8 a = *(const bf16x8*)(A + (mrow + l16) * K + kk + quad * 8);
        bf16x8 b0 = *(const bf16x8*)(BT + (n0 + l16) * K + kk + quad * 8);
        bf16x8 b1 = *(const bf16x8*)(BT + (n0 + 16 + l16) * K + kk + quad * 8);
        acc[0] = mfma16(a, b0, acc[0]);
        acc[1] = mfma16(a, b1, acc[1]);
    }
    for (int j = 0; j < 2; ++j)
        for (int r = 0; r < 4; ++r) {
            int row = mrow + quad * 4 + r;
            int col = n0 + j * 16 + l16;
            outf[(size_t)row * N_PIX + col] = acc[j][r] + rv[j * 4 + r];
        }
}

// ---------------- depthwise 3x3 + bias, vectorized ----------------
// Grid 1536 = part(3) x h(8) x y(64). Thread = (channel_in_head 0..23, 8-px segment 0..7);
// 3 bf16x8 row loads + <=6 edge scalars, 72 FMA in registers.
// part 2 (v): direct b128 store (segment = contiguous n); threads 192..255 write pad rows
// (24 = ones for row-sum trick, 25..31 = zero). part 0/1 (q/k): 8 strided b16 stores into
// [n][32] layout; threads 192..255 write the dd 24..31 zero pad as b128 (one px each).
__global__ __launch_bounds__(256) void dwconv(const bf16* __restrict__ qkv,
                                              const float* __restrict__ wdw,
                                              const float* __restrict__ bdw,
                                              bf16* __restrict__ qt,
                                              bf16* __restrict__ kt,
                                              bf16* __restrict__ vl,
                                              float* __restrict__ maxk2) {
    __shared__ float k2s[24][64];
    int bx = blockIdx.x;
    int part = bx >> 9;            // 512 blocks per part
    int h = (bx >> 6) & 7;
    int y = bx & 63;
    int t = threadIdx.x;
    int ch_local = t >> 3;         // 0..31 (24 active)
    int seg = t & 7;
    int px0 = seg * 8;
    bool active = ch_local < 24;

    float acc[8];
    if (active) {
        int ch = part * C_DIM + h * DHEAD + ch_local;
        const bf16* in = qkv + (size_t)ch * N_PIX;
        float w[9];
        for (int i = 0; i < 9; ++i) w[i] = wdw[ch * 9 + i];
        float bias = bdw[ch];
        float rowv[3][10];
        for (int r = 0; r < 3; ++r) {
            int yy = y + r - 1;
            if (yy >= 0 && yy < 64) {
                bf16x8 v8 = *(const bf16x8*)(in + yy * 64 + px0);
                for (int j = 0; j < 8; ++j) rowv[r][j + 1] = (float)v8[j];
                rowv[r][0] = (seg > 0) ? (float)in[yy * 64 + px0 - 1] : 0.f;
                rowv[r][9] = (seg < 7) ? (float)in[yy * 64 + px0 + 8] : 0.f;
            } else {
                for (int j = 0; j < 10; ++j) rowv[r][j] = 0.f;
            }
        }
        for (int j = 0; j < 8; ++j) {
            float a = bias;
            for (int r = 0; r < 3; ++r)
                a += w[r * 3 + 0] * rowv[r][j] + w[r * 3 + 1] * rowv[r][j + 1]
                   + w[r * 3 + 2] * rowv[r][j + 2];
            acc[j] = a;
        }
    }

    if (part == 2) {
        if (active) {
            bf16x8 v8;
            for (int j = 0; j < 8; ++j) v8[j] = (bf16)acc[j];
            *(bf16x8*)(vl + ((size_t)(h * DPAD + ch_local)) * N_PIX + y * 64 + px0) = v8;
        } else {
            int i = t - 192;           // 0..63: pad rows 24..31 x 8 segments
            int dd = 24 + (i >> 3);
            int s2 = i & 7;
            bf16 val = (bf16)((dd == 24) ? 1.0f : 0.0f);
            bf16x8 v8;
            for (int j = 0; j < 8; ++j) v8[j] = val;
            *(bf16x8*)(vl + ((size_t)(h * DPAD + dd)) * N_PIX + y * 64 + s2 * 8) = v8;
        }
    } else {
        bf16* dst = (part == 0 ? qt : kt) + ((size_t)h * N_PIX + y * 64) * DPAD;
        if (active) {
            for (int j = 0; j < 8; ++j)
                dst[(size_t)(px0 + j) * DPAD + ch_local] = (bf16)acc[j];
        } else {
            int i = t - 192;           // 0..63: one px each, zero dd 24..31
            bf16x8 z;
            for (int j = 0; j < 8; ++j) z[j] = (bf16)0.0f;
            *(bf16x8*)(dst + (size_t)i * DPAD + 24) = z;
        }
        if (part == 1) {
            if (active)
                for (int j = 0; j < 8; ++j) k2s[ch_local][px0 + j] = acc[j] * acc[j];
            __syncthreads();
            if (t < 64) {
                float s = 0.f;
                for (int c = 0; c < 24; ++c) s += k2s[c][t];
                for (int off = 1; off < 64; off <<= 1)
                    s = fmaxf(s, __shfl_xor(s, off, 64));
                if (t == 0) atomicMax((unsigned int*)(maxk2 + h), __float_as_uint(s));
            }
        }
    }
}

// ---------------- flash attention: fat waves (64 q/wave), no barriers, split-K=8 ----------------
__global__ __launch_bounds__(256, 4) void flash_attn(const bf16* __restrict__ qt,
                                                     const bf16* __restrict__ kt,
                                                     const bf16* __restrict__ vl,
                                                     const float* __restrict__ temp,
                                                     const float* __restrict__ maxk2,
                                                     bf16* __restrict__ opart,
                                                     bf16* __restrict__ lpart) {
    __shared__ __align__(16) bf16 Plds[4 * 4096];   // 8KB per wave: [f(4)][chunk(8)][l16(16)][8]

    int tid = threadIdx.x;
    int wave = tid >> 6, lane = tid & 63;
    int l16 = lane & 15, quad = lane >> 4;
    int head = blockIdx.x & 7;               // block -> XCD round-robin: head pinned per XCD
    int qb = (blockIdx.x >> 3) & 15;
    int split = blockIdx.x >> 7;             // 0..7
    int nbase = qb * 256 + wave * 64;
    float tl = temp[head] * 1.44269504f;

    // Q fragments (B-operand): B[n = f*16+l16][k = quad*8+j]
    const bf16* qrow = qt + ((size_t)head * N_PIX + nbase) * DPAD;
    bf16x8 aq[4];
    for (int f = 0; f < 4; ++f)
        aq[f] = *(const bf16x8*)(qrow + (size_t)(f * 16 + l16) * DPAD + quad * 8);

    // per-(f,lane) bound: B = |tl| * ||q_n|| * max||k|| + 1
    float mk2 = maxk2[head];
    float Bb[4];
    for (int f = 0; f < 4; ++f) {
        float q2 = 0.f;
        for (int j = 0; j < 8; ++j) { float v = (float)aq[f][j]; q2 += v * v; }
        q2 += __shfl_xor(q2, 16, 64);
        q2 += __shfl_xor(q2, 32, 64);
        Bb[f] = fabsf(tl) * sqrtf(q2 * mk2) + 1.0f;
    }

    const bf16* kbase = kt + (size_t)head * N_PIX * DPAD;
    const bf16* vbase = vl + (size_t)head * DPAD * N_PIX;
    bf16* pw = Plds + wave * 4096;

    f32x4 o0[4] = {}, o1[4] = {};

    #pragma unroll 2
    for (int it = 0; it < 64 / NSPLIT; ++it) {
        int m0 = (split * (64 / NSPLIT) + it) * 64;
        bf16x8 ak[4];
        for (int mt = 0; mt < 4; ++mt)
            ak[mt] = *(const bf16x8*)(kbase + (size_t)(m0 + mt * 16 + l16) * DPAD + quad * 8);
        bf16x8 av[4];
        av[0] = *(const bf16x8*)(vbase + (size_t)l16 * N_PIX + m0 + quad * 8);
        av[1] = *(const bf16x8*)(vbase + (size_t)(16 + l16) * N_PIX + m0 + quad * 8);
        av[2] = *(const bf16x8*)(vbase + (size_t)l16 * N_PIX + m0 + 32 + quad * 8);
        av[3] = *(const bf16x8*)(vbase + (size_t)(16 + l16) * N_PIX + m0 + 32 + quad * 8);

        for (int f = 0; f < 4; ++f) {
            f32x4 z = {0.f, 0.f, 0.f, 0.f};
            f32x4 st[4];
            for (int mt = 0; mt < 4; ++mt) st[mt] = mfma16(ak[mt], aq[f], z);
            for (int mt = 0; mt < 4; ++mt) {
                bf16x4 pk;
                for (int r = 0; r < 4; ++r)
                    pk[r] = (bf16)fast_exp2(__builtin_fmaf(st[mt][r], tl, -Bb[f]));
                int chunk = mt * 2 + (quad >> 1);
                *(bf16x4*)(pw + f * 1024 + (chunk * 16 + l16) * 8 + (quad & 1) * 4) = pk;
            }
        }
        for (int f = 0; f < 4; ++f) {
            bf16x8 ap0 = *(const bf16x8*)(pw + f * 1024 + (quad * 16 + l16) * 8);
            bf16x8 ap1 = *(const bf16x8*)(pw + f * 1024 + ((4 + quad) * 16 + l16) * 8);
            o0[f] = mfma16(av[0], ap0, o0[f]);
            o1[f] = mfma16(av[1], ap0, o1[f]);
            o0[f] = mfma16(av[2], ap1, o0[f]);
            o1[f] = mfma16(av[3], ap1, o1[f]);
        }
    }

    for (int f = 0; f < 4; ++f) {
        int n = nbase + f * 16 + l16;
        size_t rowo = ((size_t)(split * 8 + head) * N_PIX + n) * 24;
        bf16x4 w0;
        for (int r = 0; r < 4; ++r) w0[r] = (bf16)o0[f][r];
        *(bf16x4*)(opart + rowo + quad * 4) = w0;
        if (quad < 2) {
            bf16x4 w1;
            for (int r = 0; r < 4; ++r) w1[r] = (bf16)o1[f][r];
            *(bf16x4*)(opart + rowo + 16 + quad * 4) = w1;
        }
        if (quad == 2)
            lpart[(size_t)(split * 8 + head) * N_PIX + n] = (bf16)o1[f][0];
    }
}

// ---------------- combine split-K partials -> outt[n][c] bf16 (coalesced rows) ----------------
__global__ __launch_bounds__(256) void combine(const bf16* __restrict__ opart,
                                               const bf16* __restrict__ lpart,
                                               bf16* __restrict__ outt) {
    int idx = blockIdx.x * 256 + threadIdx.x;   // 8*4096 threads, one (h,n) row each
    int n = idx & 4095;
    int h = idx >> 12;
    float acc[24];
    for (int j = 0; j < 24; ++j) acc[j] = 0.f;
    float l = 0.f;
    for (int s = 0; s < NSPLIT; ++s) {
        const bf16* row = opart + ((size_t)(s * 8 + h) * N_PIX + n) * 24;
        bf16x8 a = *(const bf16x8*)(row);
        bf16x8 b = *(const bf16x8*)(row + 8);
        bf16x8 c = *(const bf16x8*)(row + 16);
        for (int j = 0; j < 8; ++j) {
            acc[j] += (float)a[j];
            acc[8 + j] += (float)b[j];
            acc[16 + j] += (float)c[j];
        }
        l += (float)lpart[(size_t)(s * 8 + h) * N_PIX + n];
    }
    float inv = 1.0f / l;
    bf16* dst = outt + (size_t)n * C_DIM + h * DHEAD;
    for (int g = 0; g < 3; ++g) {
        bf16x8 w;
        for (int j = 0; j < 8; ++j) w[j] = (bf16)(acc[g * 8 + j] * inv);
        *(bf16x8*)(dst + g * 8) = w;
    }
}

extern "C" void kernel_launch(void* const* d_in, const int* in_sizes, int n_in,
                              void* d_out, int out_size, void* d_ws, size_t ws_size,
                              hipStream_t stream) {
    const float* x     = (const float*)d_in[0];
    const float* gamma = (const float*)d_in[1];
    const float* beta  = (const float*)d_in[2];
    const float* wqkv  = (const float*)d_in[3];
    const float* wdw   = (const float*)d_in[4];
    const float* bdw   = (const float*)d_in[5];
    const float* wproj = (const float*)d_in[6];
    const float* temp  = (const float*)d_in[7];
    float* out = (float*)d_out;

    char* ws = (char*)d_ws;
    bf16* wqkv_b  = (bf16*)(ws + 0);          // 221184
    bf16* wproj_b = (bf16*)(ws + 221184);     // 73728
    bf16* xln     = (bf16*)(ws + 294912);     // 1572864
    bf16* qkv     = (bf16*)(ws + 1867776);    // 4718592
    bf16* qt      = (bf16*)(ws + 6586368);    // 2097152  (reused as outt after flash)
    bf16* kt      = (bf16*)(ws + 8683520);    // 2097152
    bf16* vl      = (bf16*)(ws + 10780672);   // 2097152
    bf16* opart   = (bf16*)(ws + 12877824);   // 8*8*4096*24*2 = 12582912
    bf16* lpart   = (bf16*)(ws + 25460736);   // 8*8*4096*2 = 524288
    float* maxk2  = (float*)(ws + 25985024);  // 32
    bf16* outt    = qt;                       // qt dead after flash

    prep_ln<<<688, 256, 0, stream>>>(x, gamma, beta, xln, wqkv, wproj, wqkv_b, wproj_b, maxk2);
    gemm192<<<dim3(64, 9), 256, 0, stream>>>(wqkv_b, xln, qkv);
    dwconv<<<1536, 256, 0, stream>>>(qkv, wdw, bdw, qt, kt, vl, maxk2);
    flash_attn<<<NSPLIT * 128, 256, 0, stream>>>(qt, kt, vl, temp, maxk2, opart, lpart);
    combine<<<128, 256, 0, stream>>>(opart, lpart, outt);
    gemm_proj<<<dim3(128, 3), 256, 0, stream>>>(wproj_b, outt, out, x);
}